// Round 3
// baseline (366.050 us; speedup 1.0000x reference)
//
#include <hip/hip_runtime.h>
#include <math.h>

#define NBLK 784
#define O_ 32
#define N_ 144
#define D_ 16
#define PS 20    // padded LDS row stride for P (floats): 20n mod 32 distinct over n%8
#define RS 148   // padded LDS row stride for R (floats)

// 512 threads: o = t>>4 (32 capsules), s4 = t&15 -> h = s4>>3 (l-half), sn = s4&7 (n-slice)
// Each thread owns d-components m = i*2+lh  <->  d = i*4 + 2h + lh   (8 of 16)
__global__ __launch_bounds__(512, 4) void convcaps_em(
    const float* __restrict__ poses,
    const float* __restrict__ acts,
    const float* __restrict__ kern,
    const float* __restrict__ beta_a,
    const float* __restrict__ beta_u,
    float* __restrict__ out)
{
    const int pix = blockIdx.x;          // b*196 + ho*14 + wo
    const int b  = pix / 196;
    const int hw = pix - b * 196;
    const int ho = hw / 14;
    const int wo = hw - ho * 14;

    __shared__ __align__(16) float P[N_ * PS];   // pose blocks [n][d]
    __shared__ float A[N_];                      // a_in
    __shared__ float Rm[O_ * RS];                // R / logits [o][n]

    const int t = threadIdx.x;

    // ---- load pose block: P[n][d] = poses[b, ho+ki, wo+kj, c, d], n=(ki*3+kj)*16+c
    for (int idx = t; idx < N_ * D_; idx += 512) {
        int n = idx >> 4, d = idx & 15;
        int ki = n / 48, kj = (n >> 4) - ki * 3, c = n & 15;
        P[n * PS + d] = poses[((b * 16 + ho + ki) * 16 + (wo + kj)) * 256 + c * 16 + d];
    }
    if (t < N_) {
        int n = t;
        int ki = n / 48, kj = (n >> 4) - ki * 3, c = n & 15;
        A[n] = acts[((b * 16 + ho + ki) * 16 + (wo + kj)) * 16 + c];
    }
    for (int idx = t; idx < O_ * N_; idx += 512) {
        int oo = idx / N_;
        int nn = idx - oo * N_;
        Rm[oo * RS + nn] = 0.03125f;             // 1/O
    }
    __syncthreads();

    const int o  = t >> 4;
    const int s4 = t & 15;
    const int h  = s4 >> 3;                      // l-half: columns {2h, 2h+1}
    const int sn = s4 & 7;                       // n-slice
    const float bu = beta_a == beta_u ? 0.f : beta_u[o]; // (defensive no-op; see below)
    const float ba = beta_a[o];
    const float buv = beta_u[o];
    // per-thread K base: columns 2h,2h+1 of each 4x4 block
    const float* Kh = kern + (size_t)o * (N_ * D_) + 2 * h;

    float a_out = 0.f;
    float mu8[8];

    for (int it = 0; it < 3; ++it) {
        // ===== pass 1: S1 = sum r*V, S2 = sum r*V^2 (own 8 d's), rs = sum r =====
        float S1[8], S2[8];
#pragma unroll
        for (int m = 0; m < 8; ++m) { S1[m] = 0.f; S2[m] = 0.f; }
        float rs = 0.f;

        for (int k = 0; k < 18; ++k) {
            const int n = sn + (k << 3);
            const float r = Rm[o * RS + n] * A[n];
            rs += r;
            float pv[16], kv[8];
            const float4* Pp = (const float4*)(P + n * PS);
            ((float4*)pv)[0] = Pp[0];
            ((float4*)pv)[1] = Pp[1];
            ((float4*)pv)[2] = Pp[2];
            ((float4*)pv)[3] = Pp[3];
            const float* Kn = Kh + n * D_;
#pragma unroll
            for (int j = 0; j < 4; ++j)
                *(float2*)(kv + 2 * j) = *(const float2*)(Kn + 4 * j);
#pragma unroll
            for (int i = 0; i < 4; ++i) {
#pragma unroll
                for (int lh = 0; lh < 2; ++lh) {
                    // V[i*4 + 2h+lh] = sum_j P[n][i*4+j] * K[o,n][j*4 + 2h+lh]
                    float v = fmaf(pv[i*4+0], kv[0+lh],
                              fmaf(pv[i*4+1], kv[2+lh],
                              fmaf(pv[i*4+2], kv[4+lh],
                                   pv[i*4+3] * kv[6+lh])));
                    S1[i*2+lh] = fmaf(r, v, S1[i*2+lh]);
                    S2[i*2+lh] = fmaf(r * v, v, S2[i*2+lh]);
                }
            }
        }

        // allreduce over the 8 n-slices (butterfly within wave; bits 0..2 of lane)
#pragma unroll
        for (int m = 1; m < 8; m <<= 1) {
            rs += __shfl_xor(rs, m, 64);
#pragma unroll
            for (int d = 0; d < 8; ++d) {
                S1[d] += __shfl_xor(S1[d], m, 64);
                S2[d] += __shfl_xor(S2[d], m, 64);
            }
        }

        rs += 1e-9f;                              // r_sum = sum r + EPS
        const float inv_rs = 1.0f / rs;
        float sg[8];
#pragma unroll
        for (int d = 0; d < 8; ++d) {
            mu8[d] = S1[d] * inv_rs;
            sg[d] = fmaf(-mu8[d], mu8[d], S2[d] * inv_rs) + 1e-9f;
        }
        // L_half = sum over own 8 d's of log(sigma2), via pairwise products (static idx)
        float lp = logf(sg[0] * sg[1]) + logf(sg[2] * sg[3])
                 + logf(sg[4] * sg[5]) + logf(sg[6] * sg[7]);
        const float L = lp + __shfl_xor(lp, 8, 64);   // add other half
        // cost = rs * (D*beta_u + 0.5*L);  a_out = sigmoid(inv_temp*(ba - cost))
        const float cost = rs * fmaf(0.5f, L, 16.0f * buv);
        const float x = (float)(it + 1) * (ba - cost);
        a_out = 1.0f / (1.0f + expf(-x));

        if (it < 2) {
            float is[8];
#pragma unroll
            for (int d = 0; d < 8; ++d) is[d] = 1.0f / sg[d];
            // logits = log(a_out+eps) - 0.5*(D*log(2pi) + L) - 0.5*Q
            const float LC = logf(a_out + 1e-9f)
                           - 0.5f * (16.0f * 1.8378770664093453f + L);
            __syncthreads();   // all pass-1 reads of Rm done before overwrite

            // ===== pass 2: logits into Rm =====
            for (int k = 0; k < 18; ++k) {
                const int n = sn + (k << 3);
                float pv[16], kv[8];
                const float4* Pp = (const float4*)(P + n * PS);
                ((float4*)pv)[0] = Pp[0];
                ((float4*)pv)[1] = Pp[1];
                ((float4*)pv)[2] = Pp[2];
                ((float4*)pv)[3] = Pp[3];
                const float* Kn = Kh + n * D_;
#pragma unroll
                for (int j = 0; j < 4; ++j)
                    *(float2*)(kv + 2 * j) = *(const float2*)(Kn + 4 * j);
                float Q = 0.f;
#pragma unroll
                for (int i = 0; i < 4; ++i) {
#pragma unroll
                    for (int lh = 0; lh < 2; ++lh) {
                        float v = fmaf(pv[i*4+0], kv[0+lh],
                                  fmaf(pv[i*4+1], kv[2+lh],
                                  fmaf(pv[i*4+2], kv[4+lh],
                                       pv[i*4+3] * kv[6+lh])));
                        const float df = v - mu8[i*2+lh];
                        Q = fmaf(df * df, is[i*2+lh], Q);
                    }
                }
                Q += __shfl_xor(Q, 8, 64);        // add other d-half
                if (h == 0)
                    Rm[o * RS + n] = fmaf(-0.5f, Q, LC);
            }
            __syncthreads();

            // ===== softmax over o, one thread per n =====
            if (t < N_) {
                float v[32];
                float mx = -1e30f;
#pragma unroll
                for (int oo = 0; oo < 32; ++oo) {
                    v[oo] = Rm[oo * RS + t];
                    mx = fmaxf(mx, v[oo]);
                }
                float sm = 0.f;
#pragma unroll
                for (int oo = 0; oo < 32; ++oo) {
                    v[oo] = expf(v[oo] - mx);
                    sm += v[oo];
                }
                const float inv = 1.0f / sm;
#pragma unroll
                for (int oo = 0; oo < 32; ++oo)
                    Rm[oo * RS + t] = v[oo] * inv;
            }
            __syncthreads();
        }
    }

    // ===== write outputs: poses [pix][o][16] then a_out [pix][o] =====
    if (sn == 0) {
        float* ob = out + (size_t)pix * 512 + o * 16 + 2 * h;
#pragma unroll
        for (int i = 0; i < 4; ++i) {
            ob[i * 4 + 0] = mu8[i * 2 + 0];
            ob[i * 4 + 1] = mu8[i * 2 + 1];
        }
        if (h == 0) out[401408 + pix * 32 + o] = a_out;
    }
}

extern "C" void kernel_launch(void* const* d_in, const int* in_sizes, int n_in,
                              void* d_out, int out_size, void* d_ws, size_t ws_size,
                              hipStream_t stream)
{
    const float* poses  = (const float*)d_in[0];
    const float* acts   = (const float*)d_in[1];
    const float* kern   = (const float*)d_in[2];
    const float* beta_a = (const float*)d_in[3];
    const float* beta_u = (const float*)d_in[4];
    float* out = (float*)d_out;
    convcaps_em<<<NBLK, 512, 0, stream>>>(poses, acts, kern, beta_a, beta_u, out);
}

// Round 4
// 116.601 us; speedup vs baseline: 3.1393x; 3.1393x over previous
//
#include <hip/hip_runtime.h>
#include <math.h>

#define NBLK 784
#define O_ 32
#define N_ 144
#define D_ 16
#define PS 20    // padded LDS row stride for P (floats); 80B rows keep float4 alignment
#define RS 148   // padded LDS row stride for R (floats)

// Load r, P-row, K-slice for k-iter kk into named register buffers (macro => static indexing)
#define LD(kk, rr, pvv, kvv) do {                                          \
    const int n_ = s + ((kk) << 3);                                        \
    rr = Rm[o * RS + n_] * A[n_];                                          \
    const float4* Pp_ = (const float4*)(P + n_ * PS);                      \
    ((float4*)(pvv))[0] = Pp_[0]; ((float4*)(pvv))[1] = Pp_[1];            \
    ((float4*)(pvv))[2] = Pp_[2]; ((float4*)(pvv))[3] = Pp_[3];            \
    const float4* Kp_ = (const float4*)(Kbase + n_ * D_);                  \
    ((float4*)(kvv))[0] = Kp_[0]; ((float4*)(kvv))[1] = Kp_[1];            \
    ((float4*)(kvv))[2] = Kp_[2]; ((float4*)(kvv))[3] = Kp_[3];            \
} while (0)

// Pass-2 load: no Rm read (logits pass doesn't need r)
#define LD2(kk, pvv, kvv) do {                                             \
    const int n_ = s + ((kk) << 3);                                        \
    const float4* Pp_ = (const float4*)(P + n_ * PS);                      \
    ((float4*)(pvv))[0] = Pp_[0]; ((float4*)(pvv))[1] = Pp_[1];            \
    ((float4*)(pvv))[2] = Pp_[2]; ((float4*)(pvv))[3] = Pp_[3];            \
    const float4* Kp_ = (const float4*)(Kbase + n_ * D_);                  \
    ((float4*)(kvv))[0] = Kp_[0]; ((float4*)(kvv))[1] = Kp_[1];            \
    ((float4*)(kvv))[2] = Kp_[2]; ((float4*)(kvv))[3] = Kp_[3];            \
} while (0)

// Accumulate S1/S2/rs from one (r, P-row, K-slice)
#define ACC(rr, pvv, kvv) do {                                             \
    rs += rr;                                                              \
    _Pragma("unroll")                                                      \
    for (int i_ = 0; i_ < 4; ++i_) {                                       \
      _Pragma("unroll")                                                    \
      for (int l_ = 0; l_ < 4; ++l_) {                                     \
        float v_ = fmaf((pvv)[i_*4+0], (kvv)[0+l_],                        \
                   fmaf((pvv)[i_*4+1], (kvv)[4+l_],                        \
                   fmaf((pvv)[i_*4+2], (kvv)[8+l_],                        \
                        (pvv)[i_*4+3] * (kvv)[12+l_])));                   \
        S1[i_*4+l_] = fmaf(rr, v_, S1[i_*4+l_]);                           \
        S2[i_*4+l_] = fmaf(rr * v_, v_, S2[i_*4+l_]);                      \
      }                                                                    \
    }                                                                      \
} while (0)

// Pass-2 compute: Q = sum_d (v-mu)^2/sig, write logit
#define QWR(kk, pvv, kvv) do {                                             \
    const int n_ = s + ((kk) << 3);                                        \
    float Q_ = 0.f;                                                        \
    _Pragma("unroll")                                                      \
    for (int i_ = 0; i_ < 4; ++i_) {                                       \
      _Pragma("unroll")                                                    \
      for (int l_ = 0; l_ < 4; ++l_) {                                     \
        float v_ = fmaf((pvv)[i_*4+0], (kvv)[0+l_],                        \
                   fmaf((pvv)[i_*4+1], (kvv)[4+l_],                        \
                   fmaf((pvv)[i_*4+2], (kvv)[8+l_],                        \
                        (pvv)[i_*4+3] * (kvv)[12+l_])));                   \
        const float df_ = v_ - mu[i_*4+l_];                                \
        Q_ = fmaf(df_ * df_, isg[i_*4+l_], Q_);                            \
      }                                                                    \
    }                                                                      \
    Rm[o * RS + n_] = fmaf(-0.5f, Q_, LC);                                 \
} while (0)

__global__ __launch_bounds__(256, 3) void convcaps_em(
    const float* __restrict__ poses,
    const float* __restrict__ acts,
    const float* __restrict__ kern,
    const float* __restrict__ beta_a,
    const float* __restrict__ beta_u,
    float* __restrict__ out)
{
    const int pix = blockIdx.x;          // b*196 + ho*14 + wo
    const int b  = pix / 196;
    const int hw = pix - b * 196;
    const int ho = hw / 14;
    const int wo = hw - ho * 14;

    __shared__ __align__(16) float P[N_ * PS];   // pose blocks [n][d]
    __shared__ float A[N_];                      // a_in
    __shared__ float Rm[O_ * RS];                // R / logits [o][n]

    const int t = threadIdx.x;

    // ---- load pose block: P[n][d] = poses[b, ho+ki, wo+kj, c, d], n=(ki*3+kj)*16+c
    for (int idx = t; idx < N_ * D_; idx += 256) {
        int n = idx >> 4, d = idx & 15;
        int ki = n / 48, kj = (n >> 4) - ki * 3, c = n & 15;
        P[n * PS + d] = poses[((b * 16 + ho + ki) * 16 + (wo + kj)) * 256 + c * 16 + d];
    }
    if (t < N_) {
        int n = t;
        int ki = n / 48, kj = (n >> 4) - ki * 3, c = n & 15;
        A[n] = acts[((b * 16 + ho + ki) * 16 + (wo + kj)) * 16 + c];
    }
    for (int idx = t; idx < O_ * N_; idx += 256) {
        int oo = idx / N_;
        int nn = idx - oo * N_;
        Rm[oo * RS + nn] = 0.03125f;             // 1/O
    }
    __syncthreads();

    const int o = t >> 3;                        // 32 capsules
    const int s = t & 7;                         // 8 lanes per capsule, n-slice
    const float buv = beta_u[o];
    const float ba = beta_a[o];
    const float* Kbase = kern + (size_t)o * (N_ * D_);

    float a_out = 0.f;
    float mu[16];

    for (int it = 0; it < 3; ++it) {
        // ===== pass 1 (2-deep software pipeline): S1 = Σ rV, S2 = Σ rV², rs = Σ r =====
        float S1[16], S2[16];
#pragma unroll
        for (int d = 0; d < 16; ++d) { S1[d] = 0.f; S2[d] = 0.f; }
        float rs = 0.f;

        {
            float rA, rB;
            float pvA[16], kvA[16], pvB[16], kvB[16];
            LD(0, rA, pvA, kvA);
            for (int k2 = 0; k2 < 9; ++k2) {
                LD(2 * k2 + 1, rB, pvB, kvB);
                ACC(rA, pvA, kvA);
                if (k2 < 8) LD(2 * k2 + 2, rA, pvA, kvA);
                ACC(rB, pvB, kvB);
            }
        }

        // allreduce over the 8 lanes sharing this o (butterfly, same wave)
#pragma unroll
        for (int m = 1; m < 8; m <<= 1) {
            rs += __shfl_xor(rs, m, 64);
#pragma unroll
            for (int d = 0; d < 16; ++d) {
                S1[d] += __shfl_xor(S1[d], m, 64);
                S2[d] += __shfl_xor(S2[d], m, 64);
            }
        }

        rs += 1e-9f;                              // r_sum = Σr + EPS
        const float inv_rs = 1.0f / rs;
        float sig[16];
#pragma unroll
        for (int d = 0; d < 16; ++d) {
            mu[d] = S1[d] * inv_rs;
            // sigma2 = E[V^2] - mu^2 + EPS  (== Σ r (V-mu)^2 / rs + EPS)
            sig[d] = fmaf(-mu[d], mu[d], S2[d] * inv_rs) + 1e-9f;
        }
        // L = Σ_d log(sigma2_d): lane does its 2 d's via product, 3-step butterfly
        float lpart = __logf(sig[2 * s] * sig[2 * s + 1]);
#pragma unroll
        for (int m = 1; m < 8; m <<= 1) lpart += __shfl_xor(lpart, m, 64);
        const float L = lpart;
        // cost = rs*(D*beta_u + 0.5*L);  a_out = sigmoid(inv_temp*(ba - cost))
        const float cost = rs * fmaf(0.5f, L, 16.0f * buv);
        const float x = (float)(it + 1) * (ba - cost);
        a_out = 1.0f / (1.0f + __expf(-x));

        if (it < 2) {
            float isg[16];
#pragma unroll
            for (int d = 0; d < 16; ++d) isg[d] = 1.0f / sig[d];
            // logits = log(a_out+eps) - 0.5*(D*log(2pi) + L) - 0.5*Q
            const float LC = __logf(a_out + 1e-9f)
                           - 0.5f * (16.0f * 1.8378770664093453f + L);

            float pvA[16], kvA[16], pvB[16], kvB[16];
            LD2(0, pvA, kvA);        // P/K only — safe before barrier
            __syncthreads();         // all pass-1 Rm reads done before overwrite

            // ===== pass 2 (pipelined): logits into Rm =====
            for (int k2 = 0; k2 < 9; ++k2) {
                LD2(2 * k2 + 1, pvB, kvB);
                QWR(2 * k2, pvA, kvA);
                if (k2 < 8) LD2(2 * k2 + 2, pvA, kvA);
                QWR(2 * k2 + 1, pvB, kvB);
            }
            __syncthreads();

            // ===== softmax over o, one thread per n =====
            if (t < N_) {
                float v[32];
                float mx = -1e30f;
#pragma unroll
                for (int oo = 0; oo < 32; ++oo) {
                    v[oo] = Rm[oo * RS + t];
                    mx = fmaxf(mx, v[oo]);
                }
                float sm = 0.f;
#pragma unroll
                for (int oo = 0; oo < 32; ++oo) {
                    v[oo] = __expf(v[oo] - mx);
                    sm += v[oo];
                }
                const float inv = 1.0f / sm;
#pragma unroll
                for (int oo = 0; oo < 32; ++oo)
                    Rm[oo * RS + t] = v[oo] * inv;
            }
            __syncthreads();
        }
    }

    // ===== write outputs: poses [pix][o][16] then a_out [pix][o] =====
    float2 w2;
    w2.x = mu[2 * s];
    w2.y = mu[2 * s + 1];
    *(float2*)(out + (size_t)pix * 512 + o * 16 + 2 * s) = w2;
    if (s == 0) out[401408 + pix * 32 + o] = a_out;
}

extern "C" void kernel_launch(void* const* d_in, const int* in_sizes, int n_in,
                              void* d_out, int out_size, void* d_ws, size_t ws_size,
                              hipStream_t stream)
{
    const float* poses  = (const float*)d_in[0];
    const float* acts   = (const float*)d_in[1];
    const float* kern   = (const float*)d_in[2];
    const float* beta_a = (const float*)d_in[3];
    const float* beta_u = (const float*)d_in[4];
    float* out = (float*)d_out;
    convcaps_em<<<NBLK, 256, 0, stream>>>(poses, acts, kern, beta_a, beta_u, out);
}